// Round 14
// baseline (813.061 us; speedup 1.0000x reference)
//
#include <hip/hip_runtime.h>
#include <hip/hip_fp16.h>
#include <cstdint>
#include <cmath>

#define NLEV 16
#define NHENC 9           // levels 7..15 done in encode pass (5,6 inline in mlp)
#define NDENSE 5          // levels 0..4 are dense
#define TBL (1u << 19)
#define NBKT 32768        // 32^3 spatial buckets
#define PTS 2             // points per thread in encode

typedef _Float16 half8 __attribute__((ext_vector_type(8)));
typedef float f32x4 __attribute__((ext_vector_type(4)));

struct LevelParams {
    float scale[NLEV];
    uint32_t res[NLEV];
    uint32_t hashed_mask;
};

// ---------------------------------------------------------------------------
// Prep: weight-norm; transpose W1 -> w1t[35][64]; pack MFMA B-fragments.
// Padded K=64 input-row layout: 0-2 xyz, 3 pad, 4-13 dense l0-4, 14-15 pad,
// 16-37 hashed l5-15.
// ---------------------------------------------------------------------------
__device__ __forceinline__ int krow_map(int kr) {
    if (kr <= 2) return kr;
    if (kr >= 4 && kr <= 13) return kr - 1;
    if (kr >= 16 && kr <= 37) return kr - 3;
    return -1;
}

__global__ __launch_bounds__(256) void prep_weights(
    const float* __restrict__ v1, const float* __restrict__ g1,
    const float* __restrict__ v2, const float* __restrict__ g2,
    float* __restrict__ w1t, float* __restrict__ w2n,
    __half* __restrict__ w1f, __half* __restrict__ w2f)
{
    int t = threadIdx.x;
    if (t < 64) {
        float s = 0.f;
        #pragma unroll
        for (int k = 0; k < 35; ++k) { float v = v1[t*35 + k]; s += v*v; }
        float f = g1[t] / sqrtf(s);
        #pragma unroll
        for (int k = 0; k < 35; ++k) w1t[k*64 + t] = v1[t*35 + k] * f;
    } else if (t < 77) {
        int r = t - 64;
        float s = 0.f;
        #pragma unroll
        for (int k = 0; k < 64; ++k) { float v = v2[r*64 + k]; s += v*v; }
        float f = g2[r] / sqrtf(s);
        #pragma unroll
        for (int k = 0; k < 64; ++k) w2n[r*64 + k] = v2[r*64 + k] * f;
    }
    __syncthreads();
    for (int i = t; i < 4096; i += 256) {
        int j = i & 7, lane = (i >> 3) & 63, nt = (i >> 9) & 3, kc = i >> 11;
        int kr = kc*32 + ((lane >> 4) << 3) + j;
        int ncol = nt*16 + (lane & 15);
        int m = krow_map(kr);
        float val = (m >= 0) ? w1t[m*64 + ncol] : 0.f;
        w1f[i] = __float2half(val);
    }
    for (int i = t; i < 1024; i += 256) {
        int j = i & 7, lane = (i >> 3) & 63, kc = i >> 9;
        int kr = kc*32 + ((lane >> 4) << 3) + j;
        int col = lane & 15;
        float val = (col < 13) ? w2n[col*64 + kr] : 0.f;
        w2f[i] = __float2half(val);
    }
}

// ---------------------------------------------------------------------------
// Table |max| reduce -> scaleU (float bits; nonneg floats order as uints).
// ---------------------------------------------------------------------------
__global__ __launch_bounds__(256) void max_reduce(
    const float* __restrict__ t, uint32_t* __restrict__ scaleU, int n)
{
    int i = blockIdx.x * 256 + threadIdx.x;
    float m = 0.f;
    for (int k = i; k < n; k += gridDim.x * 256) m = fmaxf(m, fabsf(t[k]));
    #pragma unroll
    for (int o = 32; o >= 1; o >>= 1) m = fmaxf(m, __shfl_xor(m, o));
    if ((threadIdx.x & 63) == 0) atomicMax(scaleU, __float_as_uint(m));
}

// ---------------------------------------------------------------------------
// Spatial bucket helpers (32^3).
// ---------------------------------------------------------------------------
__device__ __forceinline__ uint32_t bucket_key(float u0, float u1, float u2)
{
    uint32_t a = min(31u, (uint32_t)(u0 * 32.f));
    uint32_t b = min(31u, (uint32_t)(u1 * 32.f));
    uint32_t c = min(31u, (uint32_t)(u2 * 32.f));
    return (a << 10) | (b << 5) | c;
}

__device__ __forceinline__ void load_u(const float* __restrict__ x, int pp,
                                       float& u0, float& u1, float& u2)
{
    float x0 = x[3*(size_t)pp + 0];
    float x1 = x[3*(size_t)pp + 1];
    float x2 = x[3*(size_t)pp + 2];
    u0 = fminf(fmaxf(x0 + 0.5f, 0.f), 1.f);
    u1 = fminf(fmaxf(x1 + 0.5f, 0.f), 1.f);
    u2 = fminf(fmaxf(x2 + 0.5f, 0.f), 1.f);
}

// ---------------------------------------------------------------------------
// Fused: pack fp32 table -> int8 pairs (2 entries/thread -> one uint32)
// AND bucket histogram.
// ---------------------------------------------------------------------------
__device__ __forceinline__ uint32_t quant8(float v, float qs)
{
    int q = (int)rintf(v * qs);
    q = max(-127, min(127, q));
    return (uint32_t)(q & 0xff);
}

__global__ __launch_bounds__(256) void pack_and_hist(
    const float2* __restrict__ tin, uint32_t* __restrict__ tout, int n_half,
    const float* __restrict__ x, uint32_t* __restrict__ hist, int N,
    int packBlocks, const uint32_t* __restrict__ scaleU)
{
    int b = blockIdx.x;
    if (b < packBlocks) {
        int i = b * 256 + threadIdx.x;
        if (i < n_half) {
            float smax = fmaxf(__uint_as_float(*scaleU), 1e-30f);
            float qs = 127.f / smax;
            float2 a = tin[2*(size_t)i];
            float2 c = tin[2*(size_t)i + 1];
            uint32_t w = quant8(a.x, qs) | (quant8(a.y, qs) << 8)
                       | (quant8(c.x, qs) << 16) | (quant8(c.y, qs) << 24);
            tout[i] = w;
        }
    } else if (hist) {
        int i = (b - packBlocks) * 256 + threadIdx.x;
        if (i < N) {
            float u0, u1, u2;
            load_u(x, i, u0, u1, u2);
            atomicAdd(&hist[bucket_key(u0, u1, u2)], 1u);
        }
    }
}

// Proven scan: 1024 threads x 32 bins each, one block.
__global__ __launch_bounds__(1024) void scan_hist(
    const uint32_t* __restrict__ hist, uint32_t* __restrict__ offs)
{
    __shared__ uint32_t part[1024];
    int t = threadIdx.x;
    uint32_t loc[32];
    uint32_t s = 0;
    #pragma unroll
    for (int k = 0; k < 32; ++k) { loc[k] = s; s += hist[t*32 + k]; }
    part[t] = s;
    __syncthreads();
    for (int d = 1; d < 1024; d <<= 1) {
        uint32_t v = (t >= d) ? part[t - d] : 0u;
        __syncthreads();
        part[t] += v;
        __syncthreads();
    }
    uint32_t base = (t > 0) ? part[t - 1] : 0u;
    #pragma unroll
    for (int k = 0; k < 32; ++k) offs[t*32 + k] = base + loc[k];
}

__global__ __launch_bounds__(256) void scatter_kernel(
    const float* __restrict__ x, uint32_t* __restrict__ offs,
    float4* __restrict__ xs4, int N)
{
    int i = blockIdx.x * 256 + threadIdx.x;
    if (i < N) {
        float x0 = x[3*(size_t)i + 0];
        float x1 = x[3*(size_t)i + 1];
        float x2 = x[3*(size_t)i + 2];
        float u0 = fminf(fmaxf(x0 + 0.5f, 0.f), 1.f);
        float u1 = fminf(fmaxf(x1 + 0.5f, 0.f), 1.f);
        float u2 = fminf(fmaxf(x2 + 0.5f, 0.f), 1.f);
        uint32_t pos = atomicAdd(&offs[bucket_key(u0, u1, u2)], 1u);
        xs4[pos] = make_float4(x0, x1, x2, __int_as_float(i));
    }
}

// ---------------------------------------------------------------------------
// Trilinear lookup on int8 table (2B/entry), single-corner ushort loads.
// Used for dense l0-4 and near-dense hashed l5-6 (wave-shared lines).
// ---------------------------------------------------------------------------
__device__ __forceinline__ void encode_one8(
    float u0, float u1, float u2, float s, uint32_t res, bool hashed,
    const uint16_t* __restrict__ t16, float deq, float& a0, float& a1)
{
    float px = u0 * s + 0.5f;
    float py = u1 * s + 0.5f;
    float pz = u2 * s + 0.5f;
    float fx = floorf(px), fy = floorf(py), fz = floorf(pz);
    float wx1 = px - fx, wy1 = py - fy, wz1 = pz - fz;
    float wx0 = 1.f - wx1, wy0 = 1.f - wy1, wz0 = 1.f - wz1;
    uint32_t cx = (uint32_t)fx, cy = (uint32_t)fy, cz = (uint32_t)fz;

    uint32_t ix0, ix1, iy0, iy1, iz0, iz1;
    if (hashed) {
        ix0 = cx;                 ix1 = cx + 1u;
        iy0 = cy * 2654435761u;   iy1 = (cy + 1u) * 2654435761u;
        iz0 = cz * 805459861u;    iz1 = (cz + 1u) * 805459861u;
    } else {
        ix0 = cx;                 ix1 = cx + 1u;
        iy0 = cy * res;           iy1 = iy0 + res;
        uint32_t rr = res * res;
        iz0 = cz * rr;            iz1 = iz0 + rr;
    }

    uint32_t idxs[8];
    #pragma unroll
    for (int c = 0; c < 8; ++c) {
        uint32_t jx = (c & 1) ? ix1 : ix0;
        uint32_t jy = (c & 2) ? iy1 : iy0;
        uint32_t jz = (c & 4) ? iz1 : iz0;
        idxs[c] = hashed ? ((jx ^ jy ^ jz) & (TBL - 1u)) : (jx + jy + jz);
    }
    uint16_t raw[8];
    #pragma unroll
    for (int c = 0; c < 8; ++c) raw[c] = t16[idxs[c]];

    float wxy00 = wx0*wy0, wxy10 = wx1*wy0, wxy01 = wx0*wy1, wxy11 = wx1*wy1;
    a0 = 0.f; a1 = 0.f;
    #pragma unroll
    for (int c = 0; c < 8; ++c) {
        float wxy = (c & 2) ? ((c & 1) ? wxy11 : wxy01)
                            : ((c & 1) ? wxy10 : wxy00);
        float w = wxy * ((c & 4) ? wz1 : wz0);
        float f0 = (float)(int8_t)(raw[c] & 0xff);
        float f1 = (float)(int8_t)(raw[c] >> 8);
        a0 += w * f0;
        a1 += w * f1;
    }
    a0 *= deq;
    a1 *= deq;
}

// ---------------------------------------------------------------------------
// Pass A: hashed levels 7..15, ONE dispatch, level-major (1 MB int8 table
// L2-resident). Quad trick: corners cx,cx+1 share one 8B 4-entry quad when
// cx%4 != 3 (75%) -> 4 slots/pt/level; else 8 -> avg 5 (was 6 with fp16).
// par: 4 bits per k = j0(2b) | j1(2b); slow path encodes j1|=2 to pick Q.y.
// ---------------------------------------------------------------------------
template <int SORTED>
__global__ __launch_bounds__(256) void encode_hashed(
    const float* __restrict__ x, const float4* __restrict__ xs4,
    const uint8_t* __restrict__ tpk8,
    uint32_t* __restrict__ feats, int N, int chunks_per_level,
    const uint32_t* __restrict__ scaleU, LevelParams P)
{
    int bid = blockIdx.x;
    int li = bid / chunks_per_level;          // 0..NHENC-1
    int l = li + 7;                           // 7..15
    int base = (bid - li * chunks_per_level) * (256*PTS) + threadIdx.x;
    const uint8_t* tb8 = tpk8 + (size_t)l * TBL * 2u;
    float s = P.scale[l];
    float deq = __uint_as_float(*scaleU) * (1.f / 127.f);

    int p[PTS];
    #pragma unroll
    for (int t = 0; t < PTS; ++t) p[t] = base + t * 256;

    uint2 Q[PTS][4];
    uint32_t par[PTS];
    float wx0[PTS], wx1[PTS], wyz[PTS][4];

    #pragma unroll
    for (int t = 0; t < PTS; ++t) {
        int pp = (p[t] < N) ? p[t] : (N - 1);
        float u0, u1, u2;
        if (SORTED) {
            float4 v4 = xs4[pp];
            u0 = fminf(fmaxf(v4.x + 0.5f, 0.f), 1.f);
            u1 = fminf(fmaxf(v4.y + 0.5f, 0.f), 1.f);
            u2 = fminf(fmaxf(v4.z + 0.5f, 0.f), 1.f);
        } else {
            load_u(x, pp, u0, u1, u2);
        }

        float px = u0 * s + 0.5f;
        float py = u1 * s + 0.5f;
        float pz = u2 * s + 0.5f;
        float fx = floorf(px), fy = floorf(py), fz = floorf(pz);
        float a1f = px - fx, b1f = py - fy, c1f = pz - fz;
        wx1[t] = a1f; wx0[t] = 1.f - a1f;
        float wy0 = 1.f - b1f, wz0 = 1.f - c1f;
        uint32_t cx = (uint32_t)fx, cy = (uint32_t)fy, cz = (uint32_t)fz;

        wyz[t][0] = wy0 * wz0;
        wyz[t][1] = b1f * wz0;
        wyz[t][2] = wy0 * c1f;
        wyz[t][3] = b1f * c1f;

        uint32_t hy0 = cy * 2654435761u, hy1 = (cy + 1u) * 2654435761u;
        uint32_t hz0 = cz * 805459861u,  hz1 = (cz + 1u) * 805459861u;
        uint32_t r[4] = { hy0 ^ hz0, hy1 ^ hz0, hy0 ^ hz1, hy1 ^ hz1 };

        uint32_t pr = 0u;
        if ((cx & 3u) != 3u) {
            // corners share one 8B quad (hash preserves bits>=2)
            #pragma unroll
            for (int k = 0; k < 4; ++k) {
                uint32_t v0 = (cx ^ r[k]) & (TBL - 1u);
                uint32_t v1 = ((cx + 1u) ^ r[k]) & (TBL - 1u);
                Q[t][k] = *reinterpret_cast<const uint2*>(tb8 + ((v0 & ~3u) << 1));
                pr |= ((v0 & 3u) | ((v1 & 3u) << 2)) << (4*k);
            }
        } else {
            #pragma unroll
            for (int k = 0; k < 4; ++k) {
                uint32_t v0 = (cx ^ r[k]) & (TBL - 1u);
                uint32_t v1 = ((cx + 1u) ^ r[k]) & (TBL - 1u);
                Q[t][k].x = *reinterpret_cast<const uint32_t*>(tb8 + ((v0 & ~1u) << 1));
                Q[t][k].y = *reinterpret_cast<const uint32_t*>(tb8 + ((v1 & ~1u) << 1));
                pr |= ((v0 & 1u) | (((v1 & 1u) | 2u) << 2)) << (4*k);
            }
        }
        par[t] = pr;
    }

    #pragma unroll
    for (int t = 0; t < PTS; ++t) {
        float a0 = 0.f, a1 = 0.f;
        #pragma unroll
        for (int k = 0; k < 4; ++k) {
            uint32_t pk = par[t] >> (4*k);
            uint32_t j0 = pk & 3u, j1 = (pk >> 2) & 3u;
            uint32_t w0 = (j0 & 2u) ? Q[t][k].y : Q[t][k].x;
            uint32_t w1 = (j1 & 2u) ? Q[t][k].y : Q[t][k].x;
            uint32_t e0 = (j0 & 1u) ? (w0 >> 16) : (w0 & 0xffffu);
            uint32_t e1 = (j1 & 1u) ? (w1 >> 16) : (w1 & 0xffffu);
            float c0x = (float)(int8_t)(e0 & 0xff);
            float c0y = (float)(int8_t)(e0 >> 8);
            float c1x = (float)(int8_t)(e1 & 0xff);
            float c1y = (float)(int8_t)(e1 >> 8);
            a0 += wyz[t][k] * (wx0[t] * c0x + wx1[t] * c1x);
            a1 += wyz[t][k] * (wx0[t] * c0y + wx1[t] * c1y);
        }
        __half2 hv = __floats2half2_rn(a0 * deq, a1 * deq);
        if (p[t] < N) {
            __builtin_nontemporal_store(*reinterpret_cast<uint32_t*>(&hv),
                                        &feats[(size_t)li * N + p[t]]);
        }
    }
}

// ---------------------------------------------------------------------------
// Pass B (MFMA): wave owns 64 points. Dense l0-4 + near-dense l5-6 inline
// (int8 table; wave-shared lines). h-rows padded to 9 uint4 (bank-even).
// ---------------------------------------------------------------------------
__global__ __launch_bounds__(256) void mlp_mfma(
    const float4* __restrict__ xs4,
    const uint8_t* __restrict__ tpk8,
    const uint32_t* __restrict__ feats,
    const __half* __restrict__ w1f,    // [2][4][64][8]
    const __half* __restrict__ w2f,    // [2][64][8]
    const float* __restrict__ b1,
    const float* __restrict__ b2,
    const uint32_t* __restrict__ scaleU,
    float* __restrict__ out, int N, LevelParams P)
{
    __shared__ uint4 ldsA[4][576];
    __shared__ int   ldsI[4][64];
    int wid = threadIdx.x >> 6, lane = threadIdx.x & 63;
    int wpt = blockIdx.x * 256 + wid * 64;
    int pt = wpt + lane;
    int pp = (pt < N) ? pt : (N - 1);

    float4 v4 = xs4[pp];
    float x0 = v4.x, x1 = v4.y, x2 = v4.z;
    ldsI[wid][lane] = __float_as_int(v4.w);
    float u0 = fminf(fmaxf(x0 + 0.5f, 0.f), 1.f);
    float u1 = fminf(fmaxf(x1 + 0.5f, 0.f), 1.f);
    float u2 = fminf(fmaxf(x2 + 0.5f, 0.f), 1.f);
    float deq = __uint_as_float(*scaleU) * (1.f / 127.f);

    uint32_t dw[32];
    #pragma unroll
    for (int i = 0; i < 32; ++i) dw[i] = 0u;
    __half2 h01 = __floats2half2_rn(x0, x1);
    __half2 h2_ = __floats2half2_rn(x2, 0.f);
    dw[0] = *reinterpret_cast<uint32_t*>(&h01);
    dw[1] = *reinterpret_cast<uint32_t*>(&h2_);
    #pragma unroll
    for (int l = 0; l < NDENSE; ++l) {
        const uint16_t* t16 = (const uint16_t*)(tpk8 + (size_t)l * TBL * 2u);
        float a0, a1;
        encode_one8(u0, u1, u2, P.scale[l], P.res[l], false, t16, deq, a0, a1);
        __half2 hv = __floats2half2_rn(a0, a1);
        dw[2 + l] = *reinterpret_cast<uint32_t*>(&hv);
    }
    #pragma unroll
    for (int l = 5; l <= 6; ++l) {
        const uint16_t* t16 = (const uint16_t*)(tpk8 + (size_t)l * TBL * 2u);
        float a0, a1;
        encode_one8(u0, u1, u2, P.scale[l], P.res[l], true, t16, deq, a0, a1);
        __half2 hv = __floats2half2_rn(a0, a1);
        dw[8 + (l - 5)] = *reinterpret_cast<uint32_t*>(&hv);
    }
    #pragma unroll
    for (int li = 0; li < NHENC; ++li)
        dw[10 + li] = feats[(size_t)li * N + pp];

    #pragma unroll
    for (int c = 0; c < 8; ++c) {
        uint4 ch = make_uint4(dw[4*c], dw[4*c+1], dw[4*c+2], dw[4*c+3]);
        ldsA[wid][c*64 + lane] = ch;
    }

    // ---- layer 1 ----
    const uint4* w1f4 = (const uint4*)w1f;
    half8 bf[4][2];
    #pragma unroll
    for (int nt = 0; nt < 4; ++nt)
        #pragma unroll
        for (int kc = 0; kc < 2; ++kc) {
            uint4 u = w1f4[(kc*4 + nt)*64 + lane];
            bf[nt][kc] = __builtin_bit_cast(half8, u);
        }

    f32x4 C[4][4];
    #pragma unroll
    for (int nt = 0; nt < 4; ++nt) {
        float bv = b1[nt*16 + (lane & 15)];
        #pragma unroll
        for (int m = 0; m < 4; ++m) C[m][nt] = f32x4{bv, bv, bv, bv};
    }

    #pragma unroll
    for (int m = 0; m < 4; ++m) {
        uint4 ua0 = ldsA[wid][((lane >> 4)      )*64 + m*16 + (lane & 15)];
        uint4 ua1 = ldsA[wid][((lane >> 4) + 4  )*64 + m*16 + (lane & 15)];
        half8 a0 = __builtin_bit_cast(half8, ua0);
        half8 a1 = __builtin_bit_cast(half8, ua1);
        #pragma unroll
        for (int nt = 0; nt < 4; ++nt) {
            C[m][nt] = __builtin_amdgcn_mfma_f32_16x16x32_f16(a0, bf[nt][0], C[m][nt], 0, 0, 0);
            C[m][nt] = __builtin_amdgcn_mfma_f32_16x16x32_f16(a1, bf[nt][1], C[m][nt], 0, 0, 0);
        }
    }

    // ---- softplus(100x)/100 ----
    #pragma unroll
    for (int m = 0; m < 4; ++m)
        #pragma unroll
        for (int nt = 0; nt < 4; ++nt)
            #pragma unroll
            for (int r = 0; r < 4; ++r) {
                float z = 100.f * C[m][nt][r];
                float t = __expf(-fabsf(z));
                C[m][nt][r] = (fmaxf(z, 0.f) + __logf(1.f + t)) * 0.01f;
            }

    // ---- repack h -> fp16 rows [pt][36 dwords] (9 uint4, bank-even) ----
    uint32_t* hl = (uint32_t*)&ldsA[wid][0];
    bool evenl = (lane & 1) == 0;
    #pragma unroll
    for (int m = 0; m < 4; ++m)
        #pragma unroll
        for (int nt = 0; nt < 4; ++nt)
            #pragma unroll
            for (int r = 0; r < 4; ++r) {
                float self = C[m][nt][r];
                float other = __shfl_xor(self, 1);
                if (evenl) {
                    __half2 hp = __floats2half2_rn(self, other);
                    int prow = m*16 + ((lane >> 4) << 2) + r;
                    int colp = (nt*16 + (lane & 15)) >> 1;
                    hl[prow*36 + colp] = *reinterpret_cast<uint32_t*>(&hp);
                }
            }

    // ---- layer 2 ----
    const uint4* w2f4 = (const uint4*)w2f;
    half8 b2f[2];
    #pragma unroll
    for (int kc = 0; kc < 2; ++kc) {
        uint4 u = w2f4[kc*64 + lane];
        b2f[kc] = __builtin_bit_cast(half8, u);
    }
    int col = lane & 15;
    float b2v = (col < 13) ? b2[col] : 0.f;

    #pragma unroll
    for (int m = 0; m < 4; ++m) {
        uint4 ua0 = ldsA[wid][(m*16 + col)*9 + 0 + (lane >> 4)];
        uint4 ua1 = ldsA[wid][(m*16 + col)*9 + 4 + (lane >> 4)];
        f32x4 c2 = f32x4{b2v, b2v, b2v, b2v};
        c2 = __builtin_amdgcn_mfma_f32_16x16x32_f16(
                 __builtin_bit_cast(half8, ua0), b2f[0], c2, 0, 0, 0);
        c2 = __builtin_amdgcn_mfma_f32_16x16x32_f16(
                 __builtin_bit_cast(half8, ua1), b2f[1], c2, 0, 0, 0);
        #pragma unroll
        for (int r = 0; r < 4; ++r) {
            int prow = m*16 + ((lane >> 4) << 2) + r;
            if (col < 13 && wpt + prow < N) {
                int og = ldsI[wid][prow];
                out[(size_t)og * 13 + col] = c2[r];
            }
        }
    }
}

// ---------------------------------------------------------------------------
// Scalar pass B fallback (unsorted two-pass path): l0-6 inline, l7-15 feats.
// ---------------------------------------------------------------------------
__global__ __launch_bounds__(256) void mlp_dense_scalar(
    const float* __restrict__ x, const uint8_t* __restrict__ tpk8,
    const uint32_t* __restrict__ feats,
    const float* __restrict__ w1t, const float* __restrict__ b1,
    const float* __restrict__ w2, const float* __restrict__ b2,
    const uint32_t* __restrict__ scaleU,
    float* __restrict__ out, int N, LevelParams P)
{
    int p = blockIdx.x * 256 + threadIdx.x;
    bool valid = (p < N);
    int pp = valid ? p : (N - 1);

    float u0, u1, u2;
    load_u(x, pp, u0, u1, u2);
    float x0 = x[3*(size_t)pp + 0];
    float x1 = x[3*(size_t)pp + 1];
    float x2 = x[3*(size_t)pp + 2];
    float deq = __uint_as_float(*scaleU) * (1.f / 127.f);

    uint32_t rf[NHENC];
    #pragma unroll
    for (int li = 0; li < NHENC; ++li) rf[li] = feats[(size_t)li * N + pp];

    float h[64];
    #pragma unroll
    for (int j = 0; j < 64; ++j)
        h[j] = b1[j] + x0 * w1t[0*64 + j] + x1 * w1t[1*64 + j] + x2 * w1t[2*64 + j];

    #pragma unroll
    for (int l = 0; l < 7; ++l) {
        const uint16_t* t16 = (const uint16_t*)(tpk8 + (size_t)l * TBL * 2u);
        float a0, a1;
        encode_one8(u0, u1, u2, P.scale[l], P.res[l], l >= NDENSE, t16, deq, a0, a1);
        const float* c0p = w1t + (3 + 2*l) * 64;
        const float* c1p = c0p + 64;
        #pragma unroll
        for (int j = 0; j < 64; ++j) h[j] += a0 * c0p[j] + a1 * c1p[j];
    }
    #pragma unroll
    for (int li = 0; li < NHENC; ++li) {
        __half2 hv = *reinterpret_cast<__half2*>(&rf[li]);
        float2 f = __half22float2(hv);
        int l = li + 7;
        const float* c0p = w1t + (3 + 2*l) * 64;
        const float* c1p = c0p + 64;
        #pragma unroll
        for (int j = 0; j < 64; ++j) h[j] += f.x * c0p[j] + f.y * c1p[j];
    }
    #pragma unroll
    for (int j = 0; j < 64; ++j) {
        float z = 100.f * h[j];
        float t = __expf(-fabsf(z));
        h[j] = (fmaxf(z, 0.f) + __logf(1.f + t)) * 0.01f;
    }
    float* op = out + (size_t)pp * 13;
    for (int o = 0; o < 13; ++o) {
        float a = b2[o];
        const float* wr = w2 + o * 64;
        #pragma unroll
        for (int k = 0; k < 64; ++k) a = fmaf(h[k], wr[k], a);
        if (valid) op[o] = a;
    }
}

// ---------------------------------------------------------------------------
// Fused fallback (ws too small): raw fp32 table.
// ---------------------------------------------------------------------------
__global__ __launch_bounds__(256) void sdf_fused_f32(
    const float* __restrict__ x, const float* __restrict__ table,
    const float* __restrict__ w1t, const float* __restrict__ b1,
    const float* __restrict__ w2, const float* __restrict__ b2,
    float* __restrict__ out, int N, LevelParams P)
{
    int i = blockIdx.x * 256 + threadIdx.x;
    bool valid = (i < N);
    int ii = valid ? i : (N - 1);

    float x0 = x[3*(size_t)ii + 0];
    float x1 = x[3*(size_t)ii + 1];
    float x2 = x[3*(size_t)ii + 2];
    float u0 = fminf(fmaxf(x0 + 0.5f, 0.f), 1.f);
    float u1 = fminf(fmaxf(x1 + 0.5f, 0.f), 1.f);
    float u2 = fminf(fmaxf(x2 + 0.5f, 0.f), 1.f);

    float h[64];
    #pragma unroll
    for (int j = 0; j < 64; ++j)
        h[j] = b1[j] + x0 * w1t[0*64 + j] + x1 * w1t[1*64 + j] + x2 * w1t[2*64 + j];

    for (int l = 0; l < NLEV; ++l) {
        bool hashed = (P.hashed_mask >> l) & 1u;
        const float* tl = table + (size_t)l * (size_t)(TBL * 2u);
        float s = P.scale[l]; uint32_t res = P.res[l];
        float px = u0*s + 0.5f, py = u1*s + 0.5f, pz = u2*s + 0.5f;
        float fx = floorf(px), fy = floorf(py), fz = floorf(pz);
        float wx1 = px-fx, wy1 = py-fy, wz1 = pz-fz;
        float wx0 = 1.f-wx1, wy0 = 1.f-wy1, wz0 = 1.f-wz1;
        uint32_t cx = (uint32_t)fx, cy = (uint32_t)fy, cz = (uint32_t)fz;
        float a0 = 0.f, a1 = 0.f;
        #pragma unroll
        for (int c = 0; c < 8; ++c) {
            uint32_t jx = cx + (c & 1);
            uint32_t jy = cy + ((c >> 1) & 1);
            uint32_t jz = cz + ((c >> 2) & 1);
            uint32_t idx = hashed
                ? ((jx ^ (jy * 2654435761u) ^ (jz * 805459861u)) & (TBL - 1u))
                : (jx + jy * res + jz * res * res);
            float w = ((c & 1) ? wx1 : wx0) * ((c & 2) ? wy1 : wy0)
                    * ((c & 4) ? wz1 : wz0);
            float2 v = *reinterpret_cast<const float2*>(tl + (size_t)idx * 2u);
            a0 += w * v.x; a1 += w * v.y;
        }
        const float* c0p = w1t + (3 + 2*l) * 64;
        const float* c1p = c0p + 64;
        #pragma unroll
        for (int j = 0; j < 64; ++j) h[j] += a0 * c0p[j] + a1 * c1p[j];
    }

    #pragma unroll
    for (int j = 0; j < 64; ++j) {
        float z = 100.f * h[j];
        float t = __expf(-fabsf(z));
        h[j] = (fmaxf(z, 0.f) + __logf(1.f + t)) * 0.01f;
    }

    float* op = out + (size_t)ii * 13;
    for (int o = 0; o < 13; ++o) {
        float a = b2[o];
        const float* wr = w2 + o * 64;
        #pragma unroll
        for (int k = 0; k < 64; ++k) a += h[k] * wr[k];
        if (valid) op[o] = a;
    }
}

extern "C" void kernel_launch(void* const* d_in, const int* in_sizes, int n_in,
                              void* d_out, int out_size, void* d_ws, size_t ws_size,
                              hipStream_t stream)
{
    const float* x     = (const float*)d_in[0];
    const float* table = (const float*)d_in[1];
    const float* v1    = (const float*)d_in[2];
    const float* g1    = (const float*)d_in[3];
    const float* b1    = (const float*)d_in[4];
    const float* v2    = (const float*)d_in[5];
    const float* g2    = (const float*)d_in[6];
    const float* b2    = (const float*)d_in[7];
    float* out = (float*)d_out;
    int N = in_sizes[0] / 3;

    const int n_entries = NLEV * (int)TBL;                        // 8.4M
    const size_t tpk8_bytes  = (size_t)n_entries * 2u;            // 16.8 MB
    const size_t xs4_bytes   = (size_t)N * 16u;                   // 33.6 MB
    const size_t feats_bytes = (size_t)NHENC * (size_t)N * 4u;    // 75 MB
    const size_t hist_bytes  = (size_t)NBKT * 4u;                 // 128 KB
    const size_t w_bytes     = (35*64 + 13*64) * sizeof(float);
    const size_t wf_bytes    = (4096 + 1024) * sizeof(__half);    // 10 KB

    // layout: tpk8 | xs4 | feats | w | wf | scale(4B)
    // hist+offs overlay the head of feats (dead before encode writes feats).
    size_t off_tpk8  = 0;
    size_t off_xs4   = off_tpk8 + tpk8_bytes;
    size_t off_feats = off_xs4 + xs4_bytes;
    size_t off_w     = off_feats + feats_bytes;
    size_t off_wf    = off_w + w_bytes;
    size_t off_scale = off_wf + wf_bytes;
    size_t sorted_need = off_scale + 16;
    bool overlay_ok = feats_bytes >= 2 * hist_bytes;

    bool sorted_ok = (ws_size >= sorted_need) && overlay_ok;
    bool two_pass  = (ws_size >= tpk8_bytes + feats_bytes + w_bytes + wf_bytes + 16);
    bool packed_ok = (ws_size >= tpk8_bytes + w_bytes + wf_bytes + 16);

    uint8_t* tpk8 = (uint8_t*)((char*)d_ws + off_tpk8);
    float4*  xs4  = (float4*)((char*)d_ws + off_xs4);
    uint32_t* feats;
    float* w1t;
    if (sorted_ok) {
        feats = (uint32_t*)((char*)d_ws + off_feats);
        w1t = (float*)((char*)d_ws + off_w);
    } else if (two_pass) {
        feats = (uint32_t*)((char*)d_ws + tpk8_bytes);
        w1t = (float*)((char*)d_ws + tpk8_bytes + feats_bytes);
    } else {
        feats = nullptr;
        w1t = (float*)((char*)d_ws + (packed_ok ? tpk8_bytes : 0));
    }
    uint32_t* hist = feats;                    // overlay (sorted path only)
    uint32_t* offs = feats ? feats + NBKT : nullptr;
    float* w2n = w1t + 35 * 64;
    __half* w1f = (__half*)(w2n + 13 * 64);
    __half* w2f = w1f + 4096;
    uint32_t* scaleU = (uint32_t*)(w2f + 1024);

    LevelParams P;
    P.hashed_mask = 0u;
    double pls = pow(128.0, 1.0 / 15.0);
    for (int l = 0; l < NLEV; ++l) {
        double sc = 16.0 * pow(pls, (double)l) - 1.0;
        P.scale[l] = (float)sc;
        uint32_t res = (uint32_t)(ceil(sc)) + 1u;
        P.res[l] = res;
        uint64_t r3 = (uint64_t)res * res * res;
        if (r3 > (uint64_t)TBL) P.hashed_mask |= (1u << l);
    }

    prep_weights<<<1, 256, 0, stream>>>(v1, g1, v2, g2, w1t, w2n, w1f, w2f);

    int chunks = (N + 255) / 256;
    int n_half = n_entries / 2;
    int packBlocks = (n_half + 255) / 256;
    if (sorted_ok) {
        hipMemsetAsync(hist, 0, hist_bytes, stream);
        hipMemsetAsync(scaleU, 0, 4, stream);
        max_reduce<<<2048, 256, 0, stream>>>(table, scaleU, n_entries * 2);
        pack_and_hist<<<packBlocks + chunks, 256, 0, stream>>>(
            (const float2*)table, (uint32_t*)tpk8, n_half, x, hist, N,
            packBlocks, scaleU);
        scan_hist<<<1, 1024, 0, stream>>>(hist, offs);
        scatter_kernel<<<chunks, 256, 0, stream>>>(x, offs, xs4, N);
        int chunksE = (N + 256*PTS - 1) / (256*PTS);
        encode_hashed<1><<<chunksE * NHENC, 256, 0, stream>>>(
            x, xs4, tpk8, feats, N, chunksE, scaleU, P);
        mlp_mfma<<<chunks, 256, 0, stream>>>(
            xs4, tpk8, feats, w1f, w2f, b1, b2, scaleU, out, N, P);
    } else if (two_pass) {
        hipMemsetAsync(scaleU, 0, 4, stream);
        max_reduce<<<2048, 256, 0, stream>>>(table, scaleU, n_entries * 2);
        pack_and_hist<<<packBlocks, 256, 0, stream>>>(
            (const float2*)table, (uint32_t*)tpk8, n_half, x, nullptr, 0,
            packBlocks, scaleU);
        int chunksE = (N + 256*PTS - 1) / (256*PTS);
        encode_hashed<0><<<chunksE * NHENC, 256, 0, stream>>>(
            x, nullptr, tpk8, feats, N, chunksE, scaleU, P);
        mlp_dense_scalar<<<chunks, 256, 0, stream>>>(
            x, tpk8, feats, w1t, b1, w2n, b2, scaleU, out, N, P);
    } else {
        sdf_fused_f32<<<chunks, 256, 0, stream>>>(
            x, table, w1t, b1, w2n, b2, out, N, P);
    }
}

// Round 15
// 706.290 us; speedup vs baseline: 1.1512x; 1.1512x over previous
//
#include <hip/hip_runtime.h>
#include <hip/hip_fp16.h>
#include <cstdint>
#include <cmath>

#define NLEV 16
#define NHENC 9           // levels 7..15 done in encode pass (5,6 inline in mlp)
#define NDENSE 5          // levels 0..4 are dense
#define TBL (1u << 19)
#define NBKT 32768        // 32^3 spatial buckets (5 bits/axis)
#define PTS 2             // points per thread in encode

typedef _Float16 half8 __attribute__((ext_vector_type(8)));
typedef float f32x4 __attribute__((ext_vector_type(4)));

struct LevelParams {
    float scale[NLEV];
    uint32_t res[NLEV];
    uint32_t hashed_mask;
};

// ---------------------------------------------------------------------------
// Prep: weight-norm; transpose W1 -> w1t[35][64]; pack MFMA B-fragments.
// Padded K=64 input-row layout (fp16 index -> source):
//   0-2: xyz, 3: pad, 4-13: dense lvl0-4, 14-15: pad, 16-37: hashed lvl5-15
// ---------------------------------------------------------------------------
__device__ __forceinline__ int krow_map(int kr) {
    if (kr <= 2) return kr;
    if (kr >= 4 && kr <= 13) return kr - 1;
    if (kr >= 16 && kr <= 37) return kr - 3;
    return -1;
}

__global__ __launch_bounds__(256) void prep_weights(
    const float* __restrict__ v1, const float* __restrict__ g1,
    const float* __restrict__ v2, const float* __restrict__ g2,
    float* __restrict__ w1t, float* __restrict__ w2n,
    __half* __restrict__ w1f, __half* __restrict__ w2f)
{
    int t = threadIdx.x;
    if (t < 64) {
        float s = 0.f;
        #pragma unroll
        for (int k = 0; k < 35; ++k) { float v = v1[t*35 + k]; s += v*v; }
        float f = g1[t] / sqrtf(s);
        #pragma unroll
        for (int k = 0; k < 35; ++k) w1t[k*64 + t] = v1[t*35 + k] * f;
    } else if (t < 77) {
        int r = t - 64;
        float s = 0.f;
        #pragma unroll
        for (int k = 0; k < 64; ++k) { float v = v2[r*64 + k]; s += v*v; }
        float f = g2[r] / sqrtf(s);
        #pragma unroll
        for (int k = 0; k < 64; ++k) w2n[r*64 + k] = v2[r*64 + k] * f;
    }
    __syncthreads();
    for (int i = t; i < 4096; i += 256) {
        int j = i & 7, lane = (i >> 3) & 63, nt = (i >> 9) & 3, kc = i >> 11;
        int kr = kc*32 + ((lane >> 4) << 3) + j;
        int ncol = nt*16 + (lane & 15);
        int m = krow_map(kr);
        float val = (m >= 0) ? w1t[m*64 + ncol] : 0.f;
        w1f[i] = __float2half(val);
    }
    for (int i = t; i < 1024; i += 256) {
        int j = i & 7, lane = (i >> 3) & 63, kc = i >> 9;
        int kr = kc*32 + ((lane >> 4) << 3) + j;
        int col = lane & 15;
        float val = (col < 13) ? w2n[col*64 + kr] : 0.f;
        w2f[i] = __float2half(val);
    }
}

// ---------------------------------------------------------------------------
// Spatial bucket helpers (32^3).
// ---------------------------------------------------------------------------
__device__ __forceinline__ uint32_t bucket_key(float u0, float u1, float u2)
{
    uint32_t a = min(31u, (uint32_t)(u0 * 32.f));
    uint32_t b = min(31u, (uint32_t)(u1 * 32.f));
    uint32_t c = min(31u, (uint32_t)(u2 * 32.f));
    return (a << 10) | (b << 5) | c;
}

__device__ __forceinline__ void load_u(const float* __restrict__ x, int pp,
                                       float& u0, float& u1, float& u2)
{
    float x0 = x[3*(size_t)pp + 0];
    float x1 = x[3*(size_t)pp + 1];
    float x2 = x[3*(size_t)pp + 2];
    u0 = fminf(fmaxf(x0 + 0.5f, 0.f), 1.f);
    u1 = fminf(fmaxf(x1 + 0.5f, 0.f), 1.f);
    u2 = fminf(fmaxf(x2 + 0.5f, 0.f), 1.f);
}

// ---------------------------------------------------------------------------
// Fused: pack fp32 table -> fp16x2 dwords  AND  bucket histogram.
// ---------------------------------------------------------------------------
__global__ __launch_bounds__(256) void pack_and_hist(
    const float2* __restrict__ tin, uint32_t* __restrict__ tout, int n_entries,
    const float* __restrict__ x, uint32_t* __restrict__ hist, int N,
    int packBlocks)
{
    int b = blockIdx.x;
    if (b < packBlocks) {
        int i = b * 256 + threadIdx.x;
        if (i < n_entries) {
            float2 v = tin[i];
            __half2 h = __floats2half2_rn(v.x, v.y);
            tout[i] = *reinterpret_cast<uint32_t*>(&h);
        }
    } else if (hist) {
        int i = (b - packBlocks) * 256 + threadIdx.x;
        if (i < N) {
            float u0, u1, u2;
            load_u(x, i, u0, u1, u2);
            atomicAdd(&hist[bucket_key(u0, u1, u2)], 1u);
        }
    }
}

// Proven scan: 1024 threads x 32 bins each, one block.
__global__ __launch_bounds__(1024) void scan_hist(
    const uint32_t* __restrict__ hist, uint32_t* __restrict__ offs)
{
    __shared__ uint32_t part[1024];
    int t = threadIdx.x;
    uint32_t loc[32];
    uint32_t s = 0;
    #pragma unroll
    for (int k = 0; k < 32; ++k) { loc[k] = s; s += hist[t*32 + k]; }
    part[t] = s;
    __syncthreads();
    for (int d = 1; d < 1024; d <<= 1) {
        uint32_t v = (t >= d) ? part[t - d] : 0u;
        __syncthreads();
        part[t] += v;
        __syncthreads();
    }
    uint32_t base = (t > 0) ? part[t - 1] : 0u;
    #pragma unroll
    for (int k = 0; k < 32; ++k) offs[t*32 + k] = base + loc[k];
}

__global__ __launch_bounds__(256) void scatter_kernel(
    const float* __restrict__ x, uint32_t* __restrict__ offs,
    float4* __restrict__ xs4, int N)
{
    int i = blockIdx.x * 256 + threadIdx.x;
    if (i < N) {
        float x0 = x[3*(size_t)i + 0];
        float x1 = x[3*(size_t)i + 1];
        float x2 = x[3*(size_t)i + 2];
        float u0 = fminf(fmaxf(x0 + 0.5f, 0.f), 1.f);
        float u1 = fminf(fmaxf(x1 + 0.5f, 0.f), 1.f);
        float u2 = fminf(fmaxf(x2 + 0.5f, 0.f), 1.f);
        uint32_t pos = atomicAdd(&offs[bucket_key(u0, u1, u2)], 1u);
        xs4[pos] = make_float4(x0, x1, x2, __int_as_float(i));
    }
}

// ---------------------------------------------------------------------------
// Trilinear lookup (packed fp16x2 table) — dense + near-dense levels.
// ---------------------------------------------------------------------------
__device__ __forceinline__ void encode_one(
    float u0, float u1, float u2, float s, uint32_t res, bool hashed,
    const uint32_t* __restrict__ tl, float& a0, float& a1)
{
    float px = u0 * s + 0.5f;
    float py = u1 * s + 0.5f;
    float pz = u2 * s + 0.5f;
    float fx = floorf(px), fy = floorf(py), fz = floorf(pz);
    float wx1 = px - fx, wy1 = py - fy, wz1 = pz - fz;
    float wx0 = 1.f - wx1, wy0 = 1.f - wy1, wz0 = 1.f - wz1;
    uint32_t cx = (uint32_t)fx, cy = (uint32_t)fy, cz = (uint32_t)fz;

    uint32_t ix0, ix1, iy0, iy1, iz0, iz1;
    if (hashed) {
        ix0 = cx;                 ix1 = cx + 1u;
        iy0 = cy * 2654435761u;   iy1 = (cy + 1u) * 2654435761u;
        iz0 = cz * 805459861u;    iz1 = (cz + 1u) * 805459861u;
    } else {
        ix0 = cx;                 ix1 = cx + 1u;
        iy0 = cy * res;           iy1 = iy0 + res;
        uint32_t rr = res * res;
        iz0 = cz * rr;            iz1 = iz0 + rr;
    }

    uint32_t idxs[8];
    #pragma unroll
    for (int c = 0; c < 8; ++c) {
        uint32_t jx = (c & 1) ? ix1 : ix0;
        uint32_t jy = (c & 2) ? iy1 : iy0;
        uint32_t jz = (c & 4) ? iz1 : iz0;
        idxs[c] = hashed ? ((jx ^ jy ^ jz) & (TBL - 1u)) : (jx + jy + jz);
    }
    uint32_t raw[8];
    #pragma unroll
    for (int c = 0; c < 8; ++c) raw[c] = tl[idxs[c]];

    float wxy00 = wx0*wy0, wxy10 = wx1*wy0, wxy01 = wx0*wy1, wxy11 = wx1*wy1;
    a0 = 0.f; a1 = 0.f;
    #pragma unroll
    for (int c = 0; c < 8; ++c) {
        float wxy = (c & 2) ? ((c & 1) ? wxy11 : wxy01)
                            : ((c & 1) ? wxy10 : wxy00);
        float w = wxy * ((c & 4) ? wz1 : wz0);
        __half2 hv = *reinterpret_cast<__half2*>(&raw[c]);
        float2 v = __half22float2(hv);
        a0 += w * v.x;
        a1 += w * v.y;
    }
}

// ---------------------------------------------------------------------------
// Pass A: hashed levels 7..15 (9 levels), ONE dispatch, level-major (2 MB
// table L2-resident). Even-cx corner pairs = one aligned dwordx2 (8B is the
// max useful width; wider loads cost proportional TCP beats — round 9).
// int8+quad variant regressed (round 14: VALU select cost ate slot gains).
// ---------------------------------------------------------------------------
template <int SORTED>
__global__ __launch_bounds__(256) void encode_hashed(
    const float* __restrict__ x, const float4* __restrict__ xs4,
    const uint32_t* __restrict__ tpk,
    uint32_t* __restrict__ feats, int N, int chunks_per_level, LevelParams P)
{
    int bid = blockIdx.x;
    int li = bid / chunks_per_level;          // 0..NHENC-1
    int l = li + 7;                           // 7..15
    int base = (bid - li * chunks_per_level) * (256*PTS) + threadIdx.x;
    const uint32_t* tl = tpk + (size_t)l * TBL;
    float s = P.scale[l];

    int p[PTS];
    #pragma unroll
    for (int t = 0; t < PTS; ++t) p[t] = base + t * 256;

    uint2 Q[PTS][4];
    uint32_t par[PTS];
    float wx0[PTS], wx1[PTS], wyz[PTS][4];

    #pragma unroll
    for (int t = 0; t < PTS; ++t) {
        int pp = (p[t] < N) ? p[t] : (N - 1);
        float u0, u1, u2;
        if (SORTED) {
            float4 v4 = xs4[pp];
            u0 = fminf(fmaxf(v4.x + 0.5f, 0.f), 1.f);
            u1 = fminf(fmaxf(v4.y + 0.5f, 0.f), 1.f);
            u2 = fminf(fmaxf(v4.z + 0.5f, 0.f), 1.f);
        } else {
            load_u(x, pp, u0, u1, u2);
        }

        float px = u0 * s + 0.5f;
        float py = u1 * s + 0.5f;
        float pz = u2 * s + 0.5f;
        float fx = floorf(px), fy = floorf(py), fz = floorf(pz);
        float a1f = px - fx, b1f = py - fy, c1f = pz - fz;
        wx1[t] = a1f; wx0[t] = 1.f - a1f;
        float wy0 = 1.f - b1f, wz0 = 1.f - c1f;
        uint32_t cx = (uint32_t)fx, cy = (uint32_t)fy, cz = (uint32_t)fz;

        wyz[t][0] = wy0 * wz0;
        wyz[t][1] = b1f * wz0;
        wyz[t][2] = wy0 * c1f;
        wyz[t][3] = b1f * c1f;

        uint32_t hy0 = cy * 2654435761u, hy1 = (cy + 1u) * 2654435761u;
        uint32_t hz0 = cz * 805459861u,  hz1 = (cz + 1u) * 805459861u;
        uint32_t r[4] = { hy0 ^ hz0, hy1 ^ hz0, hy0 ^ hz1, hy1 ^ hz1 };

        par[t] = 0u;
        if (!(cx & 1u)) {
            // even cx: {cx^r, (cx+1)^r} = {v, v^1} -> one aligned 8B load
            #pragma unroll
            for (int k = 0; k < 4; ++k) {
                uint32_t v0 = (cx ^ r[k]) & (TBL - 1u);
                Q[t][k] = *reinterpret_cast<const uint2*>(tl + (v0 & ~1u));
                par[t] |= (v0 & 1u) << k;
            }
        } else {
            #pragma unroll
            for (int k = 0; k < 4; ++k) {
                uint32_t v0 = (cx ^ r[k]) & (TBL - 1u);
                uint32_t v1 = ((cx + 1u) ^ r[k]) & (TBL - 1u);
                Q[t][k].x = tl[v0];
                Q[t][k].y = tl[v1];
            }
        }
    }

    #pragma unroll
    for (int t = 0; t < PTS; ++t) {
        float a0 = 0.f, a1 = 0.f;
        #pragma unroll
        for (int k = 0; k < 4; ++k) {
            uint32_t swap = (par[t] >> k) & 1u;
            uint32_t b0 = swap ? Q[t][k].y : Q[t][k].x;
            uint32_t b1 = swap ? Q[t][k].x : Q[t][k].y;
            __half2 h0 = *reinterpret_cast<__half2*>(&b0);
            __half2 h1 = *reinterpret_cast<__half2*>(&b1);
            float2 c0 = __half22float2(h0);
            float2 c1 = __half22float2(h1);
            a0 += wyz[t][k] * (wx0[t] * c0.x + wx1[t] * c1.x);
            a1 += wyz[t][k] * (wx0[t] * c0.y + wx1[t] * c1.y);
        }
        __half2 hv = __floats2half2_rn(a0, a1);
        if (p[t] < N) {
            __builtin_nontemporal_store(*reinterpret_cast<uint32_t*>(&hv),
                                        &feats[(size_t)li * N + p[t]]);
        }
    }
}

// ---------------------------------------------------------------------------
// Pass B (MFMA): wave owns 64 points. Dense 0-4 AND near-dense hashed 5-6
// inline (sorted waves share their lines; ~5.3 MB hot tables ~ L2-resident).
// h-rows padded to 9 uint4 (bank-even). Plain cached loads.
// ---------------------------------------------------------------------------
__global__ __launch_bounds__(256) void mlp_mfma(
    const float4* __restrict__ xs4,
    const uint32_t* __restrict__ tpk,
    const uint32_t* __restrict__ feats,
    const __half* __restrict__ w1f,    // [2][4][64][8]
    const __half* __restrict__ w2f,    // [2][64][8]
    const float* __restrict__ b1,
    const float* __restrict__ b2,
    float* __restrict__ out, int N, LevelParams P)
{
    __shared__ uint4 ldsA[4][576];     // stage: [c 0..7][pt 0..63]; repack: [pt][9]
    __shared__ int   ldsI[4][64];
    int wid = threadIdx.x >> 6, lane = threadIdx.x & 63;
    int wpt = blockIdx.x * 256 + wid * 64;
    int pt = wpt + lane;
    int pp = (pt < N) ? pt : (N - 1);

    float4 v4 = xs4[pp];
    float x0 = v4.x, x1 = v4.y, x2 = v4.z;
    ldsI[wid][lane] = __float_as_int(v4.w);
    float u0 = fminf(fmaxf(x0 + 0.5f, 0.f), 1.f);
    float u1 = fminf(fmaxf(x1 + 0.5f, 0.f), 1.f);
    float u2 = fminf(fmaxf(x2 + 0.5f, 0.f), 1.f);

    // padded 64-fp16 input row (32 dwords = 8 uint4 chunks)
    uint32_t dw[32];
    #pragma unroll
    for (int i = 0; i < 32; ++i) dw[i] = 0u;
    __half2 h01 = __floats2half2_rn(x0, x1);
    __half2 h2_ = __floats2half2_rn(x2, 0.f);
    dw[0] = *reinterpret_cast<uint32_t*>(&h01);
    dw[1] = *reinterpret_cast<uint32_t*>(&h2_);
    #pragma unroll
    for (int l = 0; l < NDENSE; ++l) {
        const uint32_t* tl = tpk + (size_t)l * TBL;
        float a0, a1;
        encode_one(u0, u1, u2, P.scale[l], P.res[l], false, tl, a0, a1);
        __half2 hv = __floats2half2_rn(a0, a1);
        dw[2 + l] = *reinterpret_cast<uint32_t*>(&hv);
    }
    // near-dense hashed levels 5,6 inline
    #pragma unroll
    for (int l = 5; l <= 6; ++l) {
        const uint32_t* tl = tpk + (size_t)l * TBL;
        float a0, a1;
        encode_one(u0, u1, u2, P.scale[l], P.res[l], true, tl, a0, a1);
        __half2 hv = __floats2half2_rn(a0, a1);
        dw[8 + (l - 5)] = *reinterpret_cast<uint32_t*>(&hv);
    }
    // hashed levels 7..15 from encode pass
    #pragma unroll
    for (int li = 0; li < NHENC; ++li)
        dw[10 + li] = feats[(size_t)li * N + pp];

    #pragma unroll
    for (int c = 0; c < 8; ++c) {
        uint4 ch = make_uint4(dw[4*c], dw[4*c+1], dw[4*c+2], dw[4*c+3]);
        ldsA[wid][c*64 + lane] = ch;
    }

    // ---- layer 1 ----
    const uint4* w1f4 = (const uint4*)w1f;
    half8 bf[4][2];
    #pragma unroll
    for (int nt = 0; nt < 4; ++nt)
        #pragma unroll
        for (int kc = 0; kc < 2; ++kc) {
            uint4 u = w1f4[(kc*4 + nt)*64 + lane];
            bf[nt][kc] = __builtin_bit_cast(half8, u);
        }

    f32x4 C[4][4];
    #pragma unroll
    for (int nt = 0; nt < 4; ++nt) {
        float bv = b1[nt*16 + (lane & 15)];
        #pragma unroll
        for (int m = 0; m < 4; ++m) C[m][nt] = f32x4{bv, bv, bv, bv};
    }

    #pragma unroll
    for (int m = 0; m < 4; ++m) {
        uint4 ua0 = ldsA[wid][((lane >> 4)      )*64 + m*16 + (lane & 15)];
        uint4 ua1 = ldsA[wid][((lane >> 4) + 4  )*64 + m*16 + (lane & 15)];
        half8 a0 = __builtin_bit_cast(half8, ua0);
        half8 a1 = __builtin_bit_cast(half8, ua1);
        #pragma unroll
        for (int nt = 0; nt < 4; ++nt) {
            C[m][nt] = __builtin_amdgcn_mfma_f32_16x16x32_f16(a0, bf[nt][0], C[m][nt], 0, 0, 0);
            C[m][nt] = __builtin_amdgcn_mfma_f32_16x16x32_f16(a1, bf[nt][1], C[m][nt], 0, 0, 0);
        }
    }

    // ---- softplus(100x)/100 ----
    #pragma unroll
    for (int m = 0; m < 4; ++m)
        #pragma unroll
        for (int nt = 0; nt < 4; ++nt)
            #pragma unroll
            for (int r = 0; r < 4; ++r) {
                float z = 100.f * C[m][nt][r];
                float t = __expf(-fabsf(z));
                C[m][nt][r] = (fmaxf(z, 0.f) + __logf(1.f + t)) * 0.01f;
            }

    // ---- repack h -> fp16 rows [pt][36 dwords] (9 uint4, bank-even) ----
    uint32_t* hl = (uint32_t*)&ldsA[wid][0];
    bool evenl = (lane & 1) == 0;
    #pragma unroll
    for (int m = 0; m < 4; ++m)
        #pragma unroll
        for (int nt = 0; nt < 4; ++nt)
            #pragma unroll
            for (int r = 0; r < 4; ++r) {
                float self = C[m][nt][r];
                float other = __shfl_xor(self, 1);
                if (evenl) {
                    __half2 hp = __floats2half2_rn(self, other);
                    int prow = m*16 + ((lane >> 4) << 2) + r;
                    int colp = (nt*16 + (lane & 15)) >> 1;
                    hl[prow*36 + colp] = *reinterpret_cast<uint32_t*>(&hp);
                }
            }

    // ---- layer 2 ----
    const uint4* w2f4 = (const uint4*)w2f;
    half8 b2f[2];
    #pragma unroll
    for (int kc = 0; kc < 2; ++kc) {
        uint4 u = w2f4[kc*64 + lane];
        b2f[kc] = __builtin_bit_cast(half8, u);
    }
    int col = lane & 15;
    float b2v = (col < 13) ? b2[col] : 0.f;

    #pragma unroll
    for (int m = 0; m < 4; ++m) {
        uint4 ua0 = ldsA[wid][(m*16 + col)*9 + 0 + (lane >> 4)];
        uint4 ua1 = ldsA[wid][(m*16 + col)*9 + 4 + (lane >> 4)];
        f32x4 c2 = f32x4{b2v, b2v, b2v, b2v};
        c2 = __builtin_amdgcn_mfma_f32_16x16x32_f16(
                 __builtin_bit_cast(half8, ua0), b2f[0], c2, 0, 0, 0);
        c2 = __builtin_amdgcn_mfma_f32_16x16x32_f16(
                 __builtin_bit_cast(half8, ua1), b2f[1], c2, 0, 0, 0);
        #pragma unroll
        for (int r = 0; r < 4; ++r) {
            int prow = m*16 + ((lane >> 4) << 2) + r;
            if (col < 13 && wpt + prow < N) {
                int og = ldsI[wid][prow];
                out[(size_t)og * 13 + col] = c2[r];
            }
        }
    }
}

// ---------------------------------------------------------------------------
// Scalar pass B fallback (unsorted two-pass path): l0-6 inline, l7-15 feats.
// ---------------------------------------------------------------------------
__global__ __launch_bounds__(256) void mlp_dense_scalar(
    const float* __restrict__ x, const uint32_t* __restrict__ tpk,
    const uint32_t* __restrict__ feats,
    const float* __restrict__ w1t, const float* __restrict__ b1,
    const float* __restrict__ w2, const float* __restrict__ b2,
    float* __restrict__ out, int N, LevelParams P)
{
    int p = blockIdx.x * 256 + threadIdx.x;
    bool valid = (p < N);
    int pp = valid ? p : (N - 1);

    float u0, u1, u2;
    load_u(x, pp, u0, u1, u2);
    float x0 = x[3*(size_t)pp + 0];
    float x1 = x[3*(size_t)pp + 1];
    float x2 = x[3*(size_t)pp + 2];

    uint32_t rf[NHENC];
    #pragma unroll
    for (int li = 0; li < NHENC; ++li) rf[li] = feats[(size_t)li * N + pp];

    float h[64];
    #pragma unroll
    for (int j = 0; j < 64; ++j)
        h[j] = b1[j] + x0 * w1t[0*64 + j] + x1 * w1t[1*64 + j] + x2 * w1t[2*64 + j];

    #pragma unroll
    for (int l = 0; l < 7; ++l) {
        const uint32_t* tl = tpk + (size_t)l * TBL;
        float a0, a1;
        encode_one(u0, u1, u2, P.scale[l], P.res[l], l >= NDENSE, tl, a0, a1);
        const float* c0p = w1t + (3 + 2*l) * 64;
        const float* c1p = c0p + 64;
        #pragma unroll
        for (int j = 0; j < 64; ++j) h[j] += a0 * c0p[j] + a1 * c1p[j];
    }
    #pragma unroll
    for (int li = 0; li < NHENC; ++li) {
        __half2 hv = *reinterpret_cast<__half2*>(&rf[li]);
        float2 f = __half22float2(hv);
        int l = li + 7;
        const float* c0p = w1t + (3 + 2*l) * 64;
        const float* c1p = c0p + 64;
        #pragma unroll
        for (int j = 0; j < 64; ++j) h[j] += f.x * c0p[j] + f.y * c1p[j];
    }
    #pragma unroll
    for (int j = 0; j < 64; ++j) {
        float z = 100.f * h[j];
        float t = __expf(-fabsf(z));
        h[j] = (fmaxf(z, 0.f) + __logf(1.f + t)) * 0.01f;
    }
    float* op = out + (size_t)pp * 13;
    for (int o = 0; o < 13; ++o) {
        float a = b2[o];
        const float* wr = w2 + o * 64;
        #pragma unroll
        for (int k = 0; k < 64; ++k) a = fmaf(h[k], wr[k], a);
        if (valid) op[o] = a;
    }
}

// ---------------------------------------------------------------------------
// Fused fallback (ws too small): raw fp32 table.
// ---------------------------------------------------------------------------
__global__ __launch_bounds__(256) void sdf_fused_f32(
    const float* __restrict__ x, const float* __restrict__ table,
    const float* __restrict__ w1t, const float* __restrict__ b1,
    const float* __restrict__ w2, const float* __restrict__ b2,
    float* __restrict__ out, int N, LevelParams P)
{
    int i = blockIdx.x * 256 + threadIdx.x;
    bool valid = (i < N);
    int ii = valid ? i : (N - 1);

    float x0 = x[3*(size_t)ii + 0];
    float x1 = x[3*(size_t)ii + 1];
    float x2 = x[3*(size_t)ii + 2];
    float u0 = fminf(fmaxf(x0 + 0.5f, 0.f), 1.f);
    float u1 = fminf(fmaxf(x1 + 0.5f, 0.f), 1.f);
    float u2 = fminf(fmaxf(x2 + 0.5f, 0.f), 1.f);

    float h[64];
    #pragma unroll
    for (int j = 0; j < 64; ++j)
        h[j] = b1[j] + x0 * w1t[0*64 + j] + x1 * w1t[1*64 + j] + x2 * w1t[2*64 + j];

    for (int l = 0; l < NLEV; ++l) {
        bool hashed = (P.hashed_mask >> l) & 1u;
        const float* tl = table + (size_t)l * (size_t)(TBL * 2u);
        float s = P.scale[l]; uint32_t res = P.res[l];
        float px = u0*s + 0.5f, py = u1*s + 0.5f, pz = u2*s + 0.5f;
        float fx = floorf(px), fy = floorf(py), fz = floorf(pz);
        float wx1 = px-fx, wy1 = py-fy, wz1 = pz-fz;
        float wx0 = 1.f-wx1, wy0 = 1.f-wy1, wz0 = 1.f-wz1;
        uint32_t cx = (uint32_t)fx, cy = (uint32_t)fy, cz = (uint32_t)fz;
        float a0 = 0.f, a1 = 0.f;
        #pragma unroll
        for (int c = 0; c < 8; ++c) {
            uint32_t jx = cx + (c & 1);
            uint32_t jy = cy + ((c >> 1) & 1);
            uint32_t jz = cz + ((c >> 2) & 1);
            uint32_t idx = hashed
                ? ((jx ^ (jy * 2654435761u) ^ (jz * 805459861u)) & (TBL - 1u))
                : (jx + jy * res + jz * res * res);
            float w = ((c & 1) ? wx1 : wx0) * ((c & 2) ? wy1 : wy0)
                    * ((c & 4) ? wz1 : wz0);
            float2 v = *reinterpret_cast<const float2*>(tl + (size_t)idx * 2u);
            a0 += w * v.x; a1 += w * v.y;
        }
        const float* c0p = w1t + (3 + 2*l) * 64;
        const float* c1p = c0p + 64;
        #pragma unroll
        for (int j = 0; j < 64; ++j) h[j] += a0 * c0p[j] + a1 * c1p[j];
    }

    #pragma unroll
    for (int j = 0; j < 64; ++j) {
        float z = 100.f * h[j];
        float t = __expf(-fabsf(z));
        h[j] = (fmaxf(z, 0.f) + __logf(1.f + t)) * 0.01f;
    }

    float* op = out + (size_t)ii * 13;
    for (int o = 0; o < 13; ++o) {
        float a = b2[o];
        const float* wr = w2 + o * 64;
        #pragma unroll
        for (int k = 0; k < 64; ++k) a += h[k] * wr[k];
        if (valid) op[o] = a;
    }
}

extern "C" void kernel_launch(void* const* d_in, const int* in_sizes, int n_in,
                              void* d_out, int out_size, void* d_ws, size_t ws_size,
                              hipStream_t stream)
{
    const float* x     = (const float*)d_in[0];
    const float* table = (const float*)d_in[1];
    const float* v1    = (const float*)d_in[2];
    const float* g1    = (const float*)d_in[3];
    const float* b1    = (const float*)d_in[4];
    const float* v2    = (const float*)d_in[5];
    const float* g2    = (const float*)d_in[6];
    const float* b2    = (const float*)d_in[7];
    float* out = (float*)d_out;
    int N = in_sizes[0] / 3;

    const int n_entries = NLEV * (int)TBL;
    const size_t packed_bytes = (size_t)n_entries * 4u;            // 32 MB
    const size_t xs4_bytes    = (size_t)N * 16u;                   // 33.6 MB
    const size_t feats_bytes  = (size_t)NHENC * (size_t)N * 4u;    // 75 MB
    const size_t hist_bytes   = (size_t)NBKT * 4u;                 // 128 KB
    const size_t w_bytes      = (35*64 + 13*64) * sizeof(float);
    const size_t wf_bytes     = (4096 + 1024) * sizeof(__half);    // 10 KB

    // layout: packed | xs4 | feats | weights
    // hist+offs OVERLAY the head of feats (dead before encode writes feats).
    size_t off_packed = 0;
    size_t off_xs4    = off_packed + packed_bytes;
    size_t off_feats  = off_xs4 + xs4_bytes;
    size_t off_w      = off_feats + feats_bytes;
    size_t off_wf     = off_w + w_bytes;
    size_t sorted_need = off_wf + wf_bytes;
    bool overlay_ok = feats_bytes >= 2 * hist_bytes;

    bool sorted_ok = (ws_size >= sorted_need) && overlay_ok;
    bool two_pass  = (ws_size >= packed_bytes + feats_bytes + w_bytes + wf_bytes);
    bool packed_ok = (ws_size >= packed_bytes + w_bytes + wf_bytes);

    uint32_t* tpk   = (uint32_t*)((char*)d_ws + off_packed);
    float4*   xs4   = (float4*)((char*)d_ws + off_xs4);
    uint32_t* feats;
    float* w1t;
    if (sorted_ok) {
        feats = (uint32_t*)((char*)d_ws + off_feats);
        w1t = (float*)((char*)d_ws + off_w);
    } else if (two_pass) {
        feats = (uint32_t*)((char*)d_ws + packed_bytes);
        w1t = (float*)((char*)d_ws + packed_bytes + feats_bytes);
    } else {
        feats = nullptr;
        w1t = (float*)((char*)d_ws + (packed_ok ? packed_bytes : 0));
    }
    uint32_t* hist = feats;                    // overlay (sorted path only)
    uint32_t* offs = feats ? feats + NBKT : nullptr;
    float* w2n = w1t + 35 * 64;
    __half* w1f = (__half*)(w2n + 13 * 64);
    __half* w2f = w1f + 4096;

    LevelParams P;
    P.hashed_mask = 0u;
    double pls = pow(128.0, 1.0 / 15.0);
    for (int l = 0; l < NLEV; ++l) {
        double sc = 16.0 * pow(pls, (double)l) - 1.0;
        P.scale[l] = (float)sc;
        uint32_t res = (uint32_t)(ceil(sc)) + 1u;
        P.res[l] = res;
        uint64_t r3 = (uint64_t)res * res * res;
        if (r3 > (uint64_t)TBL) P.hashed_mask |= (1u << l);
    }

    prep_weights<<<1, 256, 0, stream>>>(v1, g1, v2, g2, w1t, w2n, w1f, w2f);

    int chunks = (N + 255) / 256;
    int packBlocks = (n_entries + 255) / 256;
    if (sorted_ok) {
        hipMemsetAsync(hist, 0, hist_bytes, stream);
        pack_and_hist<<<packBlocks + chunks, 256, 0, stream>>>(
            (const float2*)table, tpk, n_entries, x, hist, N, packBlocks);
        scan_hist<<<1, 1024, 0, stream>>>(hist, offs);
        scatter_kernel<<<chunks, 256, 0, stream>>>(x, offs, xs4, N);
        int chunksE = (N + 256*PTS - 1) / (256*PTS);
        encode_hashed<1><<<chunksE * NHENC, 256, 0, stream>>>(
            x, xs4, tpk, feats, N, chunksE, P);
        mlp_mfma<<<chunks, 256, 0, stream>>>(
            xs4, tpk, feats, w1f, w2f, b1, b2, out, N, P);
    } else if (two_pass) {
        pack_and_hist<<<packBlocks, 256, 0, stream>>>(
            (const float2*)table, tpk, n_entries, x, nullptr, 0, packBlocks);
        int chunksE = (N + 256*PTS - 1) / (256*PTS);
        encode_hashed<0><<<chunksE * NHENC, 256, 0, stream>>>(
            x, nullptr, tpk, feats, N, chunksE, P);
        mlp_dense_scalar<<<chunks, 256, 0, stream>>>(
            x, tpk, feats, w1t, b1, w2n, b2, out, N, P);
    } else {
        sdf_fused_f32<<<chunks, 256, 0, stream>>>(
            x, table, w1t, b1, w2n, b2, out, N, P);
    }
}